// Round 9
// baseline (316.204 us; speedup 1.0000x reference)
//
#include <hip/hip_runtime.h>
#include <hip/hip_bf16.h>

typedef unsigned short u16;
typedef unsigned int u32;
typedef __attribute__((ext_vector_type(8))) short bf16x8;   // 8 bf16 = 4 VGPRs
typedef __attribute__((ext_vector_type(4))) float f32x4;
typedef __attribute__((ext_vector_type(2))) unsigned int u32x2;

#define NBATCH 4
#define DDIM   128
#define NHEAD  8
#define PTOT   12544
#define CWID   112     // patch grid width
#define NTOK   49      // tokens per 7x7 window
#define PSTR   68      // p_lds row stride (u16 elems)
#define SCALE  0.08838834764831845f

// Producer/consumer LDS layout (u16 units):
//   buf0: ts[49][128] @0 (6272), us[128][64] @6272 (8192)   -> 14464
//   buf1: @14464
//   xw  [49][128] @28928  (x window, swz128, PERSISTENT — producers read every head)
//   pl  [49][68]  @35200  (P^T, consumer-wave-private rows)
//   pcf bf16[1352]@38532
//   cs  f32[512]  @39884
// total 40908 u16 = 81816 B <= 81920 -> 2 blocks/CU = 16 waves/CU = 4 waves/SIMD.
// Role split keeps each wave's register demand under the 128-reg 4-wave budget:
// producers (waves 4-7): A(h+1) with X from LDS (~80 regs);
// consumers (waves 0-3): B/SM/P/C (~108 regs incl. 32 AGPR outacc).
// ts rows >=49 never written; stray B-reads land in us (finite bf16, sv-masked).
// xa rows >=49 masked to zero (stray xw-reads land in pl: avoid NaN*0 in C).
#define BUFSZ   14464
#define OFF_US  6272
#define OFF_XW  28928
#define OFF_PL  35200
#define OFF_PCF 38532
#define OFF_CS  39884
#define LDS_TOT 40908

__device__ __forceinline__ float bf2f(u16 u) {
    union { u32 i; float f; } x; x.i = ((u32)u) << 16; return x.f;
}
__device__ __forceinline__ u16 f2bf(float f) {
    union { float f; u32 u; } v; v.f = f;
    return (u16)((v.u + 0x7fffu + ((v.u >> 16) & 1u)) >> 16);
}
__device__ __forceinline__ u32 pk2(float a, float b) {
    union { __hip_bfloat162 h; u32 u; } c;
    float2 t; t.x = a; t.y = b;
    c.h = __float22bfloat162_rn(t);
    return c.u;
}
__device__ __forceinline__ int swz128(int row, int col) {
    return row * 128 + ((((col >> 3) ^ (row & 15)) & 15) << 3) + (col & 7);
}

// ws layout: u16 Gt (8 x 128x128, pre-scaled) | u16 Wc (8 x 128x128) | fp32 block
// fp32 block at u16 offset 262144: bcv[1024] | r[1024] | M[1024] | s[8] (r/M/s scaled)
#define WS_WC   131072
#define WS_F32  262144

// ---- prepass (128 blocks = 16 outputs x 8 row-slices) ----
// b<8 -> Wc_h = Wo_h*Wv_h + bcv; b>=8 -> Gt_h = scaled (Wk^T Wq)^T + r/M/s
__global__ void __launch_bounds__(256) prep(
    const float* __restrict__ Wq, const float* __restrict__ Wk,
    const float* __restrict__ Wv, const float* __restrict__ Wo,
    const float* __restrict__ bq, const float* __restrict__ bk,
    const float* __restrict__ bv, u16* __restrict__ ws)
{
    __shared__ u16 lm[18432];           // A-slice 16x128 @0, B 128x128 @2048
    const int tid = threadIdx.x;
    const int bb  = blockIdx.x;
    const int b   = bb >> 3;
    const int sub = bb & 7;
    const bool isG = (b >= 8);
    const int h = b & 7;
    const int r0 = sub * 16;
    float* fb = (float*)(ws + WS_F32);

    if (!isG) {
        for (int idx = tid; idx < 2048; idx += 256) {
            const int lr = idx >> 7, dh = idx & 127;
            lm[swz128(lr, dh)] = f2bf(Wo[(r0 + lr) * 1024 + h * 128 + dh]);
        }
        for (int idx = tid; idx < 16384; idx += 256) {
            const int dh = idx >> 7, d = idx & 127;
            lm[2048 + swz128(d, dh)] = f2bf(Wv[(h * 128 + dh) * 128 + d]);
        }
        if (sub == 0 && tid < 128) {
            float s = 0.f;
            for (int dh = 0; dh < 128; ++dh)
                s += Wo[tid * 1024 + h * 128 + dh] * bv[h * 128 + dh];
            fb[h * 128 + tid] = s;                 // bcv
        }
    } else {
        for (int idx = tid; idx < 2048; idx += 256) {
            const int dh = idx >> 4, lr = idx & 15;
            lm[swz128(lr, dh)] = f2bf(Wk[(h * 128 + dh) * 128 + r0 + lr]);
        }
        for (int idx = tid; idx < 16384; idx += 256) {
            const int dh = idx >> 7, dp = idx & 127;
            lm[2048 + swz128(dp, dh)] = f2bf(Wq[(h * 128 + dh) * 128 + dp]);
        }
        if (sub == 0 && tid < 128) {
            float r = 0.f, m = 0.f;
            for (int dh = 0; dh < 128; ++dh) {
                r += bk[h * 128 + dh] * Wq[(h * 128 + dh) * 128 + tid];
                m += Wk[(h * 128 + dh) * 128 + tid] * bq[h * 128 + dh];
            }
            fb[1024 + h * 128 + tid] = r * SCALE;
            fb[2048 + h * 128 + tid] = m * SCALE;
        }
        if (sub == 0 && tid == 0) {
            float s = 0.f;
            for (int dh = 0; dh < 128; ++dh) s += bk[h * 128 + dh] * bq[h * 128 + dh];
            fb[3072 + h] = s * SCALE;
        }
    }
    __syncthreads();

    const int w = tid >> 6, lane = tid & 63, quad = lane >> 4, lid = lane & 15;
    const f32x4 z4 = {0.f, 0.f, 0.f, 0.f};
    u16* dst = ws + (isG ? 0 : WS_WC) + h * 16384;
    const float gs = isG ? SCALE : 1.0f;
    bf16x8 A[4];
    #pragma unroll
    for (int kt = 0; kt < 4; ++kt)
        A[kt] = *(const bf16x8*)(lm + swz128(lid, kt * 32 + quad * 8));
    #pragma unroll
    for (int ntl = 0; ntl < 2; ++ntl) {
        const int nt = 2 * w + ntl;
        f32x4 acc = z4;
        #pragma unroll
        for (int kt = 0; kt < 4; ++kt) {
            bf16x8 B = *(const bf16x8*)(lm + 2048 + swz128(nt * 16 + lid, kt * 32 + quad * 8));
            acc = __builtin_amdgcn_mfma_f32_16x16x32_bf16(A[kt], B, acc, 0, 0, 0);
        }
        #pragma unroll
        for (int r = 0; r < 4; ++r) {
            const int row = r0 + quad * 4 + r, col = nt * 16 + lid;
            if (isG) dst[col * 128 + row] = f2bf(acc[r] * gs);
            else     dst[row * 128 + col] = f2bf(acc[r]);
        }
    }
}

// 512 threads = 8 waves per window. Waves 4-7 produce A(h+1) into buf[(h+1)&1];
// waves 0-3 consume buf[h&1] (B/SM/P/C). One uniform barrier per head.
__global__ void __launch_bounds__(512, 4)
winattn(const float* __restrict__ xg, const u16* __restrict__ ws,
        const float* __restrict__ bo, const float* __restrict__ posf,
        float* __restrict__ out)
{
    __shared__ __align__(16) u16 sm[LDS_TOT];
    u16* xw    = sm + OFF_XW;             // persistent x window
    u16* pl    = sm + OFF_PL;             // P^T, consumer-wave-private rows
    u16* pcf16 = sm + OFF_PCF;            // pos bias bf16
    float* cs  = (float*)(sm + OFF_CS);   // c_i per head

    const int tid  = threadIdx.x;
    const int w    = tid >> 6;            // 0..7
    const int lane = tid & 63;
    const int quad = lane >> 4;
    const int lid  = lane & 15;
    // XCD-aware bijective remap (R8-verified: FETCH 72->15 MB)
    const int bx0  = blockIdx.x;
    const int xcd  = bx0 & 7;
    const int idx0 = bx0 >> 3;
    const int n    = idx0 >> 5;
    const int win  = xcd * 32 + (idx0 & 31);
    const int pbase = (win >> 4) * 7 * CWID + (win & 15) * 7;

    const bf16x8 zf = {0,0,0,0,0,0,0,0};
    const f32x4  z4 = {0.f,0.f,0.f,0.f};

    const u16* Gt  = ws;
    const u16* Wcw = ws + WS_WC;
    const float* fb  = (const float*)(ws + WS_F32);
    const float* bcv = fb;
    const float* rP  = fb + 1024;
    const float* MP  = fb + 2048;
    const float* sP  = fb + 3072;

    // ---- stage pos table (bf16) + x window (persistent) ----
    for (int i = tid; i < 169 * NHEAD; i += 512) pcf16[i] = f2bf(posf[i]);
    const float* xn = xg + n * DDIM * PTOT;
    for (int idx = tid; idx < DDIM * NTOK; idx += 512) {
        int d = idx / NTOK;
        int t = idx - d * NTOK;
        int a = t / 7, b = t - a * 7;
        xw[swz128(t, d)] = f2bf(xn[d * PTOT + pbase + a * CWID + b]);
    }
    __syncthreads();

    // ---- cs: one head per wave (all 8 waves): cs[w][i] = x_i . M_w + s_w ----
    {
        const int hh = w;
        const float sh = sP[hh];
        #pragma unroll
        for (int mt = 0; mt < 4; ++mt) {
            float c = 0.f;
            #pragma unroll
            for (int kt = 0; kt < 4; ++kt) {
                bf16x8 xa = *(const bf16x8*)(xw + swz128(mt * 16 + lid, kt * 32 + quad * 8));
                #pragma unroll
                for (int jj = 0; jj < 8; ++jj)
                    c += bf2f((u16)xa[jj]) * MP[hh * 128 + kt * 32 + quad * 8 + jj];
            }
            c += __shfl_xor(c, 16);
            c += __shfl_xor(c, 32);
            if (quad == 0) cs[hh * 64 + mt * 16 + lid] = c + sh;
        }
    }

    const int j  = 16 * (w & 3) + lid;            // consumer j; producers ignore
    const int jc = j < NTOK ? j : NTOK - 1;
    const int aj = jc / 7, bj = jc - aj * 7;

    bf16x8 xq[4];
    f32x4 outacc[8];
    if (w < 4) {
        // consumer prologue: hoist own j-tile
        #pragma unroll
        for (int kt = 0; kt < 4; ++kt)
            xq[kt] = (j < NTOK)
                ? *(const bf16x8*)(xw + swz128(j, kt * 32 + quad * 8)) : zf;
        #pragma unroll
        for (int nt = 0; nt < 8; ++nt) outacc[nt] = z4;
    } else {
        // producer prologue: A(0) into buf0
        const int wp = w - 4;
        u16* tsb = sm;
        u16* usb = sm + OFF_US;
        bf16x8 GA[2][4];
        #pragma unroll
        for (int mtl = 0; mtl < 2; ++mtl)
            #pragma unroll
            for (int kt = 0; kt < 4; ++kt)
                GA[mtl][kt] = *(const bf16x8*)(Gt + ((2 * wp + mtl) * 16 + lid) * 128 + kt * 32 + quad * 8);
        #pragma unroll
        for (int nt = 0; nt < 4; ++nt) {
            bf16x8 xb[4];
            #pragma unroll
            for (int kt = 0; kt < 4; ++kt)
                xb[kt] = *(const bf16x8*)(xw + swz128(nt * 16 + lid, kt * 32 + quad * 8));
            const int i = nt * 16 + lid;
            #pragma unroll
            for (int mtl = 0; mtl < 2; ++mtl) {
                f32x4 acc = z4;
                #pragma unroll
                for (int kt = 0; kt < 4; ++kt)
                    acc = __builtin_amdgcn_mfma_f32_16x16x32_bf16(GA[mtl][kt], xb[kt], acc, 0, 0, 0);
                const int dpb = (2 * wp + mtl) * 16 + quad * 4;
                if (i < NTOK) {
                    const f32x4 rb = *(const f32x4*)(rP + dpb);
                    u32x2 pkv;
                    pkv.x = pk2(acc[0] + rb[0], acc[1] + rb[1]);
                    pkv.y = pk2(acc[2] + rb[2], acc[3] + rb[3]);
                    *(u32x2*)(tsb + i * 128 + ((((dpb >> 3) ^ (i & 15)) & 15) << 3) + (dpb & 7)) = pkv;
                }
            }
        }
        bf16x8 WB[2][4];
        float bb[2];
        #pragma unroll
        for (int ntl = 0; ntl < 2; ++ntl) {
            #pragma unroll
            for (int kt = 0; kt < 4; ++kt)
                WB[ntl][kt] = *(const bf16x8*)(Wcw + ((2 * wp + ntl) * 16 + lid) * 128 + kt * 32 + quad * 8);
            bb[ntl] = bcv[(2 * wp + ntl) * 16 + lid];
        }
        #pragma unroll
        for (int mt = 0; mt < 4; ++mt) {
            bf16x8 xa[4];
            #pragma unroll
            for (int kt = 0; kt < 4; ++kt) {
                bf16x8 v = *(const bf16x8*)(xw + swz128(mt * 16 + lid, kt * 32 + quad * 8));
                xa[kt] = (mt < 3 || (mt * 16 + lid) < NTOK) ? v : zf;  // NaN guard
            }
            const int ib = mt * 16 + quad * 4;
            #pragma unroll
            for (int ntl = 0; ntl < 2; ++ntl) {
                f32x4 acc = z4;
                #pragma unroll
                for (int kt = 0; kt < 4; ++kt)
                    acc = __builtin_amdgcn_mfma_f32_16x16x32_bf16(xa[kt], WB[ntl][kt], acc, 0, 0, 0);
                const int dd = (2 * wp + ntl) * 16 + lid;
                u32x2 pkv;
                pkv.x = pk2(acc[0] + bb[ntl], acc[1] + bb[ntl]);
                pkv.y = pk2(acc[2] + bb[ntl], acc[3] + bb[ntl]);
                *(u32x2*)(usb + dd * 64 + ((((ib >> 3) ^ (dd & 7)) & 7) << 3) + (ib & 7)) = pkv;
            }
        }
    }
    __syncthreads();   // buf0 + cs ready

    for (int h = 0; h < NHEAD; ++h) {
        if (w >= 4) {
            // ======== producer: A(h+1) into buf[(h+1)&1] ========
            if (h < NHEAD - 1) {
                const int hn = h + 1;
                const int wp = w - 4;
                u16* tsb = sm + (hn & 1) * BUFSZ;
                u16* usb = tsb + OFF_US;
                bf16x8 GA[2][4];
                #pragma unroll
                for (int mtl = 0; mtl < 2; ++mtl)
                    #pragma unroll
                    for (int kt = 0; kt < 4; ++kt)
                        GA[mtl][kt] = *(const bf16x8*)(Gt + hn * 16384 + ((2 * wp + mtl) * 16 + lid) * 128 + kt * 32 + quad * 8);
                #pragma unroll
                for (int nt = 0; nt < 4; ++nt) {
                    bf16x8 xb[4];
                    #pragma unroll
                    for (int kt = 0; kt < 4; ++kt)
                        xb[kt] = *(const bf16x8*)(xw + swz128(nt * 16 + lid, kt * 32 + quad * 8));
                    const int i = nt * 16 + lid;
                    #pragma unroll
                    for (int mtl = 0; mtl < 2; ++mtl) {
                        f32x4 acc = z4;
                        #pragma unroll
                        for (int kt = 0; kt < 4; ++kt)
                            acc = __builtin_amdgcn_mfma_f32_16x16x32_bf16(GA[mtl][kt], xb[kt], acc, 0, 0, 0);
                        const int dpb = (2 * wp + mtl) * 16 + quad * 4;
                        if (i < NTOK) {
                            const f32x4 rb = *(const f32x4*)(rP + hn * 128 + dpb);
                            u32x2 pkv;
                            pkv.x = pk2(acc[0] + rb[0], acc[1] + rb[1]);
                            pkv.y = pk2(acc[2] + rb[2], acc[3] + rb[3]);
                            *(u32x2*)(tsb + i * 128 + ((((dpb >> 3) ^ (i & 15)) & 15) << 3) + (dpb & 7)) = pkv;
                        }
                    }
                }
                bf16x8 WB[2][4];
                float bb[2];
                #pragma unroll
                for (int ntl = 0; ntl < 2; ++ntl) {
                    #pragma unroll
                    for (int kt = 0; kt < 4; ++kt)
                        WB[ntl][kt] = *(const bf16x8*)(Wcw + hn * 16384 + ((2 * wp + ntl) * 16 + lid) * 128 + kt * 32 + quad * 8);
                    bb[ntl] = bcv[hn * 128 + (2 * wp + ntl) * 16 + lid];
                }
                #pragma unroll
                for (int mt = 0; mt < 4; ++mt) {
                    bf16x8 xa[4];
                    #pragma unroll
                    for (int kt = 0; kt < 4; ++kt) {
                        bf16x8 v = *(const bf16x8*)(xw + swz128(mt * 16 + lid, kt * 32 + quad * 8));
                        xa[kt] = (mt < 3 || (mt * 16 + lid) < NTOK) ? v : zf;
                    }
                    const int ib = mt * 16 + quad * 4;
                    #pragma unroll
                    for (int ntl = 0; ntl < 2; ++ntl) {
                        f32x4 acc = z4;
                        #pragma unroll
                        for (int kt = 0; kt < 4; ++kt)
                            acc = __builtin_amdgcn_mfma_f32_16x16x32_bf16(xa[kt], WB[ntl][kt], acc, 0, 0, 0);
                        const int dd = (2 * wp + ntl) * 16 + lid;
                        u32x2 pkv;
                        pkv.x = pk2(acc[0] + bb[ntl], acc[1] + bb[ntl]);
                        pkv.y = pk2(acc[2] + bb[ntl], acc[3] + bb[ntl]);
                        *(u32x2*)(usb + dd * 64 + ((((ib >> 3) ^ (dd & 7)) & 7) << 3) + (ib & 7)) = pkv;
                    }
                }
            }
        } else {
            // ======== consumer: B / SM / P / C on buf[h&1] ========
            u16* tsb = sm + (h & 1) * BUFSZ;
            u16* usb = tsb + OFF_US;

            f32x4 S[4];
            #pragma unroll
            for (int mt = 0; mt < 4; ++mt) {
                S[mt] = z4;
                #pragma unroll
                for (int kt = 0; kt < 4; ++kt) {
                    bf16x8 Abf = *(const bf16x8*)(tsb + (mt * 16 + lid) * 128 + ((((kt * 4 + quad) ^ lid) & 15) << 3));
                    S[mt] = __builtin_amdgcn_mfma_f32_16x16x32_bf16(Abf, xq[kt], S[mt], 0, 0, 0);
                }
            }
            float sv[4][4];
            float ssum = 0.f;
            #pragma unroll
            for (int mt = 0; mt < 4; ++mt)
                #pragma unroll
                for (int r = 0; r < 4; ++r) {
                    const int ii = mt * 16 + quad * 4 + r;
                    float e;
                    if (ii < NTOK) {
                        const int ai = ii / 7, bi = ii - ai * 7;
                        const int rel = (ai - aj + 6) + 13 * (bi - bj + 6);
                        e = __expf(S[mt][r] + cs[h * 64 + ii] + bf2f(pcf16[rel * NHEAD + h]));
                    } else {
                        e = 0.0f;
                    }
                    sv[mt][r] = e;
                    ssum += e;
                }
            ssum += __shfl_xor(ssum, 16);
            ssum += __shfl_xor(ssum, 32);
            const float inv = 1.0f / ssum;
            if (j < NTOK) {
                #pragma unroll
                for (int mt = 0; mt < 4; ++mt) {
                    u32x2 pkv;
                    pkv.x = pk2(sv[mt][0] * inv, sv[mt][1] * inv);
                    pkv.y = pk2(sv[mt][2] * inv, sv[mt][3] * inv);
                    *(u32x2*)(pl + j * PSTR + mt * 16 + quad * 4) = pkv;
                }
            }
            // P rows wave-private: same-wave LDS RAW needs only lgkmcnt drain
            asm volatile("s_waitcnt lgkmcnt(0)" ::: "memory");

            #pragma unroll
            for (int kt = 0; kt < 2; ++kt) {
                union { bf16x8 v; u32 u[4]; } Af;
                #pragma unroll
                for (int q2 = 0; q2 < 4; ++q2)
                    Af.u[q2] = *(const u32*)(pl + jc * PSTR + kt * 32 + quad * 8 + 2 * q2);
                #pragma unroll
                for (int nt = 0; nt < 8; ++nt) {
                    const int dd = nt * 16 + lid;
                    bf16x8 Bu = *(const bf16x8*)(usb + dd * 64 + ((((kt * 4 + quad) ^ (dd & 7)) & 7) << 3));
                    outacc[nt] = __builtin_amdgcn_mfma_f32_16x16x32_bf16(Af.v, Bu, outacc[nt], 0, 0, 0);
                }
            }
        }
        __syncthreads();   // uniform: producers done writing buf[(h+1)&1],
                           // consumers done reading buf[h&1]
    }

    // ======== epilogue (consumers): out[n][dd][p(j)] = acc + bo[dd] ========
    if (w < 4) {
        float* outp = out + n * DDIM * PTOT;
        #pragma unroll
        for (int nt = 0; nt < 8; ++nt) {
            const int dd = nt * 16 + lid;
            const float bov = bo[dd];
            #pragma unroll
            for (int r = 0; r < 4; ++r) {
                const int jj = 16 * (w & 3) + quad * 4 + r;
                if (jj < NTOK) {
                    const int a = jj / 7, b = jj - a * 7;
                    outp[dd * PTOT + pbase + a * CWID + b] = outacc[nt][r] + bov;
                }
            }
        }
    }
}

extern "C" void kernel_launch(void* const* d_in, const int* in_sizes, int n_in,
                              void* d_out, int out_size, void* d_ws, size_t ws_size,
                              hipStream_t stream) {
    (void)in_sizes; (void)n_in; (void)ws_size; (void)out_size;
    prep<<<128, 256, 0, stream>>>((const float*)d_in[1], (const float*)d_in[3],
                                  (const float*)d_in[5], (const float*)d_in[7],
                                  (const float*)d_in[2], (const float*)d_in[4],
                                  (const float*)d_in[6], (u16*)d_ws);
    winattn<<<NBATCH * 256, 512, 0, stream>>>(
        (const float*)d_in[0], (const u16*)d_ws,
        (const float*)d_in[8], (const float*)d_in[9], (float*)d_out);
}

// Round 10
// 220.531 us; speedup vs baseline: 1.4338x; 1.4338x over previous
//
#include <hip/hip_runtime.h>
#include <hip/hip_bf16.h>

typedef unsigned short u16;
typedef unsigned int u32;
typedef __attribute__((ext_vector_type(8))) short bf16x8;   // 8 bf16 = 4 VGPRs
typedef __attribute__((ext_vector_type(4))) float f32x4;
typedef __attribute__((ext_vector_type(2))) unsigned int u32x2;

#define NBATCH 4
#define DDIM   128
#define NHEAD  8
#define PTOT   12544
#define CWID   112     // patch grid width
#define NTOK   49      // tokens per 7x7 window
#define PSTR   68      // p_lds row stride (u16 elems)
#define SCALE  0.08838834764831845f

// Round-0 proven LDS layout (u16 units), double-buffered ts/us:
//   buf0: ts 64x128 @0, us 128x64 @8192 ; buf1 @16384 ; pl @32768 (49x68)
//   pcf f32[1352] @36100 ; cs f32[512] @38804 ; total 39828 u16 = 79656 B
// -> 2 blocks/CU, 2 waves/SIMD. Occupancy model (calibrated R1-R9):
// waves/SIMD = floor(512/(arch+AGPR)); this kernel needs ~192-224 total -> 2.
// Barrier is raw s_barrier + lgkmcnt(0) only (no vmcnt drain) so the GA(h+1)
// prefetch issued pre-barrier stays in flight across it (T3/T4 pattern).
#define BUFSZ   16384
#define OFF_US  8192
#define OFF_PL  32768
#define OFF_PCF 36100
#define OFF_CS  38804
#define LDS_TOT 39828

__device__ __forceinline__ float bf2f(u16 u) {
    union { u32 i; float f; } x; x.i = ((u32)u) << 16; return x.f;
}
__device__ __forceinline__ u16 f2bf(float f) {
    union { float f; u32 u; } v; v.f = f;
    return (u16)((v.u + 0x7fffu + ((v.u >> 16) & 1u)) >> 16);
}
__device__ __forceinline__ u32 pk2(float a, float b) {
    union { __hip_bfloat162 h; u32 u; } c;
    float2 t; t.x = a; t.y = b;
    c.h = __float22bfloat162_rn(t);
    return c.u;
}
__device__ __forceinline__ int swz128(int row, int col) {
    return row * 128 + ((((col >> 3) ^ (row & 15)) & 15) << 3) + (col & 7);
}

// ws layout: u16 Gt (8 x 128x128, pre-scaled) | u16 Wc (8 x 128x128) | fp32 block
// fp32 block at u16 offset 262144: bcv[1024] | r[1024] | M[1024] | s[8] (r/M/s scaled)
#define WS_WC   131072
#define WS_F32  262144

// ---- prepass (128 blocks = 16 outputs x 8 row-slices) ----
// b<8 -> Wc_h = Wo_h*Wv_h + bcv; b>=8 -> Gt_h = scaled (Wk^T Wq)^T + r/M/s
__global__ void __launch_bounds__(256) prep(
    const float* __restrict__ Wq, const float* __restrict__ Wk,
    const float* __restrict__ Wv, const float* __restrict__ Wo,
    const float* __restrict__ bq, const float* __restrict__ bk,
    const float* __restrict__ bv, u16* __restrict__ ws)
{
    __shared__ u16 lm[18432];           // A-slice 16x128 @0, B 128x128 @2048
    const int tid = threadIdx.x;
    const int bb  = blockIdx.x;
    const int b   = bb >> 3;
    const int sub = bb & 7;
    const bool isG = (b >= 8);
    const int h = b & 7;
    const int r0 = sub * 16;
    float* fb = (float*)(ws + WS_F32);

    if (!isG) {
        for (int idx = tid; idx < 2048; idx += 256) {
            const int lr = idx >> 7, dh = idx & 127;
            lm[swz128(lr, dh)] = f2bf(Wo[(r0 + lr) * 1024 + h * 128 + dh]);
        }
        for (int idx = tid; idx < 16384; idx += 256) {
            const int dh = idx >> 7, d = idx & 127;
            lm[2048 + swz128(d, dh)] = f2bf(Wv[(h * 128 + dh) * 128 + d]);
        }
        if (sub == 0 && tid < 128) {
            float s = 0.f;
            for (int dh = 0; dh < 128; ++dh)
                s += Wo[tid * 1024 + h * 128 + dh] * bv[h * 128 + dh];
            fb[h * 128 + tid] = s;                 // bcv
        }
    } else {
        for (int idx = tid; idx < 2048; idx += 256) {
            const int dh = idx >> 4, lr = idx & 15;
            lm[swz128(lr, dh)] = f2bf(Wk[(h * 128 + dh) * 128 + r0 + lr]);
        }
        for (int idx = tid; idx < 16384; idx += 256) {
            const int dh = idx >> 7, dp = idx & 127;
            lm[2048 + swz128(dp, dh)] = f2bf(Wq[(h * 128 + dh) * 128 + dp]);
        }
        if (sub == 0 && tid < 128) {
            float r = 0.f, m = 0.f;
            for (int dh = 0; dh < 128; ++dh) {
                r += bk[h * 128 + dh] * Wq[(h * 128 + dh) * 128 + tid];
                m += Wk[(h * 128 + dh) * 128 + tid] * bq[h * 128 + dh];
            }
            fb[1024 + h * 128 + tid] = r * SCALE;
            fb[2048 + h * 128 + tid] = m * SCALE;
        }
        if (sub == 0 && tid == 0) {
            float s = 0.f;
            for (int dh = 0; dh < 128; ++dh) s += bk[h * 128 + dh] * bq[h * 128 + dh];
            fb[3072 + h] = s * SCALE;
        }
    }
    __syncthreads();

    const int w = tid >> 6, lane = tid & 63, quad = lane >> 4, lid = lane & 15;
    const f32x4 z4 = {0.f, 0.f, 0.f, 0.f};
    u16* dst = ws + (isG ? 0 : WS_WC) + h * 16384;
    const float gs = isG ? SCALE : 1.0f;
    bf16x8 A[4];
    #pragma unroll
    for (int kt = 0; kt < 4; ++kt)
        A[kt] = *(const bf16x8*)(lm + swz128(lid, kt * 32 + quad * 8));
    #pragma unroll
    for (int ntl = 0; ntl < 2; ++ntl) {
        const int nt = 2 * w + ntl;
        f32x4 acc = z4;
        #pragma unroll
        for (int kt = 0; kt < 4; ++kt) {
            bf16x8 B = *(const bf16x8*)(lm + 2048 + swz128(nt * 16 + lid, kt * 32 + quad * 8));
            acc = __builtin_amdgcn_mfma_f32_16x16x32_bf16(A[kt], B, acc, 0, 0, 0);
        }
        #pragma unroll
        for (int r = 0; r < 4; ++r) {
            const int row = r0 + quad * 4 + r, col = nt * 16 + lid;
            if (isG) dst[col * 128 + row] = f2bf(acc[r] * gs);
            else     dst[row * 128 + col] = f2bf(acc[r]);
        }
    }
}

// stage B body, compile-time wave index WW so xfrag[WW] is a static register use
#define STAGE_B(WW) \
    _Pragma("unroll") \
    for (int mt = 0; mt < 4; ++mt) { \
        _Pragma("unroll") \
        for (int kt = 0; kt < 4; ++kt) { \
            bf16x8 Abf = *(const bf16x8*)(tsb + (mt * 16 + lid) * 128 + ((((kt * 4 + quad) ^ lid) & 15) << 3)); \
            S[mt] = __builtin_amdgcn_mfma_f32_16x16x32_bf16(Abf, xfrag[WW][kt], S[mt], 0, 0, 0); \
        } \
    }

// 256 threads = 4 waves; wave w owns query group j in [16w,16w+16).
// R8 + grafts: GA(h+1) prefetch issued BEFORE a counted barrier (lgkmcnt-only,
// raw s_barrier — no vmcnt drain), f32x4 cs loads, v_rcp for 1/ssum.
__global__ void __launch_bounds__(256, 2)
winattn(const float* __restrict__ xg, const u16* __restrict__ ws,
        const float* __restrict__ bo, const float* __restrict__ posf,
        float* __restrict__ out)
{
    __shared__ __align__(16) u16 sm[LDS_TOT];
    u16* xw  = sm;                       // staging overlay on buf0 ts
    u16* pl  = sm + OFF_PL;              // P^T [j][i], wave-private rows
    float* pcf = (float*)(sm + OFF_PCF); // pos bias fp32
    float* cs  = (float*)(sm + OFF_CS);  // c_i per head

    const int tid  = threadIdx.x;
    const int w    = tid >> 6;
    const int lane = tid & 63;
    const int quad = lane >> 4;
    const int lid  = lane & 15;
    // XCD-aware bijective remap (R8-verified: FETCH 72->15 MB)
    const int bx0  = blockIdx.x;
    const int xcd  = bx0 & 7;
    const int idx0 = bx0 >> 3;
    const int n    = idx0 >> 5;
    const int win  = xcd * 32 + (idx0 & 31);
    const int pbase = (win >> 4) * 7 * CWID + (win & 15) * 7;

    const bf16x8 zf = {0,0,0,0,0,0,0,0};
    const f32x4  z4 = {0.f,0.f,0.f,0.f};

    const u16* Gt  = ws;
    const u16* Wcw = ws + WS_WC;
    const float* fb  = (const float*)(ws + WS_F32);
    const float* bcv = fb;
    const float* rP  = fb + 1024;
    const float* MP  = fb + 2048;
    const float* sP  = fb + 3072;

    // ---- stage pos table + x window ----
    for (int i = tid; i < 169 * NHEAD; i += 256) pcf[i] = posf[i];
    const float* xn = xg + n * DDIM * PTOT;
    for (int idx = tid; idx < DDIM * NTOK; idx += 256) {
        int d = idx / NTOK;
        int t = idx - d * NTOK;
        int a = t / 7, b = t - a * 7;
        xw[swz128(t, d)] = f2bf(xn[d * PTOT + pbase + a * CWID + b]);
    }
    __syncthreads();

    // ---- hoist x fragments (A-layout == B-layout: lane lid = token, quad*8 = d) ----
    bf16x8 xfrag[4][4];
    #pragma unroll
    for (int mt = 0; mt < 4; ++mt)
        #pragma unroll
        for (int kt = 0; kt < 4; ++kt)
            xfrag[mt][kt] = (mt * 16 + lid < NTOK)
                ? *(const bf16x8*)(xw + swz128(mt * 16 + lid, kt * 32 + quad * 8)) : zf;
    const int j = 16 * w + lid;

    // ---- head-0 weights prefetched; c_i compute hides their latency ----
    bf16x8 GA[2][4], WBn[2][4];
    #pragma unroll
    for (int mtl = 0; mtl < 2; ++mtl)
        #pragma unroll
        for (int kt = 0; kt < 4; ++kt) {
            GA[mtl][kt]  = *(const bf16x8*)(Gt  + ((2 * w + mtl) * 16 + lid) * 128 + kt * 32 + quad * 8);
            WBn[mtl][kt] = *(const bf16x8*)(Wcw + ((2 * w + mtl) * 16 + lid) * 128 + kt * 32 + quad * 8);
        }

    // ---- c_i tables (scaled): cs[h][i] = x_i . M_h + s_h ----
    for (int hh = w; hh < NHEAD; hh += 4) {
        const float sh = sP[hh];
        #pragma unroll
        for (int mt = 0; mt < 4; ++mt) {
            float c = 0.f;
            #pragma unroll
            for (int kt = 0; kt < 4; ++kt)
                #pragma unroll
                for (int jj = 0; jj < 8; ++jj)
                    c += bf2f((u16)xfrag[mt][kt][jj]) * MP[hh * 128 + kt * 32 + quad * 8 + jj];
            c += __shfl_xor(c, 16);
            c += __shfl_xor(c, 32);
            if (quad == 0) cs[hh * 64 + mt * 16 + lid] = c + sh;
        }
    }
    __syncthreads();   // xw dead (buffers overlay); cs visible

    f32x4 outacc[8];
    #pragma unroll
    for (int nt = 0; nt < 8; ++nt) outacc[nt] = z4;

    const int jc = j < NTOK ? j : NTOK - 1;
    const int aj = jc / 7, bj = jc - aj * 7;   // head-invariant

    #pragma unroll 2
    for (int h = 0; h < NHEAD; ++h) {
        u16* tsb = sm + (h & 1) * BUFSZ;            // T^T as ts[i][d'] swizzled
        u16* usb = tsb + OFF_US;                    // U as us[dd][i] swizzled

        __builtin_amdgcn_s_setprio(1);
        // ======== stage A: T^T = G_h x X^T (+r) — prefetched GA ========
        #pragma unroll
        for (int mtl = 0; mtl < 2; ++mtl) {
            const int mt = 2 * w + mtl;             // d'-tile
            const f32x4 rb = *(const f32x4*)(rP + h * 128 + mt * 16 + quad * 4);
            const int dpb = mt * 16 + quad * 4;     // d' base for this lane's 4 outputs
            #pragma unroll
            for (int nt = 0; nt < 4; ++nt) {        // i-tiles
                f32x4 acc = z4;
                #pragma unroll
                for (int kt = 0; kt < 4; ++kt)
                    acc = __builtin_amdgcn_mfma_f32_16x16x32_bf16(GA[mtl][kt], xfrag[nt][kt], acc, 0, 0, 0);
                const int i = nt * 16 + lid;
                u32x2 pkv;
                pkv.x = pk2(acc[0] + rb[0], acc[1] + rb[1]);
                pkv.y = pk2(acc[2] + rb[2], acc[3] + rb[3]);
                *(u32x2*)(tsb + i * 128 + ((((dpb >> 3) ^ (i & 15)) & 15) << 3) + (dpb & 7)) = pkv;
            }
        }
        // ======== stage A: U = X x Wc_h^T (+bcv) — prefetched WBn ========
        #pragma unroll
        for (int ntl = 0; ntl < 2; ++ntl) {
            const int nt = 2 * w + ntl;             // dd-tile
            const int dd = nt * 16 + lid;
            const float bb = bcv[h * 128 + dd];
            #pragma unroll
            for (int mt = 0; mt < 4; ++mt) {        // i-tiles
                f32x4 acc = z4;
                #pragma unroll
                for (int kt = 0; kt < 4; ++kt)
                    acc = __builtin_amdgcn_mfma_f32_16x16x32_bf16(xfrag[mt][kt], WBn[ntl][kt], acc, 0, 0, 0);
                const int ib = mt * 16 + quad * 4;  // i base
                u32x2 pkv;
                pkv.x = pk2(acc[0] + bb, acc[1] + bb);
                pkv.y = pk2(acc[2] + bb, acc[3] + bb);
                *(u32x2*)(usb + dd * 64 + ((((ib >> 3) ^ (dd & 7)) & 7) << 3) + (ib & 7)) = pkv;
            }
        }
        __builtin_amdgcn_s_setprio(0);

        // ---- prefetch next head's GA BEFORE the barrier: stays in flight
        //      across it (counted barrier below has no vmcnt drain) ----
        {
            const int hn = (h + 1) & 7;
            #pragma unroll
            for (int mtl = 0; mtl < 2; ++mtl)
                #pragma unroll
                for (int kt = 0; kt < 4; ++kt)
                    GA[mtl][kt] = *(const bf16x8*)(Gt + hn * 16384 + ((2 * w + mtl) * 16 + lid) * 128 + kt * 32 + quad * 8);
        }

        // counted barrier: A's ds_writes must be visible (lgkmcnt 0) but global
        // prefetches may remain in flight (no vmcnt drain — unlike __syncthreads)
        asm volatile("s_waitcnt lgkmcnt(0)" ::: "memory");
        __builtin_amdgcn_s_barrier();
        asm volatile("" ::: "memory");

        // ======== stage B: S = T x X_j^T (+cs+pos), softmax (no max-shift) ========
        f32x4 S[4];
        #pragma unroll
        for (int mt = 0; mt < 4; ++mt) S[mt] = z4;
        __builtin_amdgcn_s_setprio(1);
        if      (w == 0) { STAGE_B(0) }
        else if (w == 1) { STAGE_B(1) }
        else if (w == 2) { STAGE_B(2) }
        else             { STAGE_B(3) }
        __builtin_amdgcn_s_setprio(0);

        float sv[4][4];
        float ssum = 0.f;
        #pragma unroll
        for (int mt = 0; mt < 4; ++mt) {
            const f32x4 csv = *(const f32x4*)(cs + h * 64 + mt * 16 + quad * 4);
            #pragma unroll
            for (int r = 0; r < 4; ++r) {
                const int ii = mt * 16 + quad * 4 + r;
                float e;
                if (ii < NTOK) {
                    const int ai = ii / 7, bi = ii - ai * 7;
                    const int rel = (ai - aj + 6) + 13 * (bi - bj + 6);
                    e = __expf(S[mt][r] + csv[r] + pcf[rel * NHEAD + h]);
                } else {
                    e = 0.0f;
                }
                sv[mt][r] = e;
                ssum += e;
            }
        }
        ssum += __shfl_xor(ssum, 16);
        ssum += __shfl_xor(ssum, 32);
        const float inv = __builtin_amdgcn_rcpf(ssum);   // ~1e-5 rel err << bf16 P
        if (j < NTOK) {
            #pragma unroll
            for (int mt = 0; mt < 4; ++mt) {
                u32x2 pkv;
                pkv.x = pk2(sv[mt][0] * inv, sv[mt][1] * inv);
                pkv.y = pk2(sv[mt][2] * inv, sv[mt][3] * inv);
                *(u32x2*)(pl + j * PSTR + mt * 16 + quad * 4) = pkv;
            }
        }

        // ---- prefetch next head's WB: live range covers only stage C ----
        {
            const int hn = (h + 1) & 7;
            #pragma unroll
            for (int ntl = 0; ntl < 2; ++ntl)
                #pragma unroll
                for (int kt = 0; kt < 4; ++kt)
                    WBn[ntl][kt] = *(const bf16x8*)(Wcw + hn * 16384 + ((2 * w + ntl) * 16 + lid) * 128 + kt * 32 + quad * 8);
        }

        // P rows are wave-private: same-wave LDS RAW needs only an lgkmcnt drain.
        asm volatile("s_waitcnt lgkmcnt(0)" ::: "memory");

        // ======== stage C: outacc += P^T x U ========
        __builtin_amdgcn_s_setprio(1);
        #pragma unroll
        for (int kt = 0; kt < 2; ++kt) {
            union { bf16x8 v; u32 u[4]; } Af;
            #pragma unroll
            for (int q2 = 0; q2 < 4; ++q2)
                Af.u[q2] = *(const u32*)(pl + jc * PSTR + kt * 32 + quad * 8 + 2 * q2);
            #pragma unroll
            for (int nt = 0; nt < 8; ++nt) {
                const int dd = nt * 16 + lid;
                bf16x8 Bu = *(const bf16x8*)(usb + dd * 64 + ((((kt * 4 + quad) ^ (dd & 7)) & 7) << 3));
                outacc[nt] = __builtin_amdgcn_mfma_f32_16x16x32_bf16(Af.v, Bu, outacc[nt], 0, 0, 0);
            }
        }
        __builtin_amdgcn_s_setprio(0);
        // no end-of-head barrier: next head writes the OTHER ts/us buffer
    }

    // ======== epilogue: out[n][dd][p(j)] = acc + bo[dd]  (fp32 output) ========
    float* outp = out + n * DDIM * PTOT;
    #pragma unroll
    for (int nt = 0; nt < 8; ++nt) {
        const int dd = nt * 16 + lid;
        const float bov = bo[dd];
        #pragma unroll
        for (int r = 0; r < 4; ++r) {
            const int jj = 16 * w + quad * 4 + r;
            if (jj < NTOK) {
                const int a = jj / 7, b = jj - a * 7;
                outp[dd * PTOT + pbase + a * CWID + b] = outacc[nt][r] + bov;
            }
        }
    }
}

extern "C" void kernel_launch(void* const* d_in, const int* in_sizes, int n_in,
                              void* d_out, int out_size, void* d_ws, size_t ws_size,
                              hipStream_t stream) {
    (void)in_sizes; (void)n_in; (void)ws_size; (void)out_size;
    prep<<<128, 256, 0, stream>>>((const float*)d_in[1], (const float*)d_in[3],
                                  (const float*)d_in[5], (const float*)d_in[7],
                                  (const float*)d_in[2], (const float*)d_in[4],
                                  (const float*)d_in[6], (u16*)d_ws);
    winattn<<<NBATCH * 256, 256, 0, stream>>>(
        (const float*)d_in[0], (const u16*)d_ws,
        (const float*)d_in[8], (const float*)d_in[9], (float*)d_out);
}

// Round 11
// 211.167 us; speedup vs baseline: 1.4974x; 1.0443x over previous
//
#include <hip/hip_runtime.h>
#include <hip/hip_bf16.h>

typedef unsigned short u16;
typedef unsigned int u32;
typedef __attribute__((ext_vector_type(8))) short bf16x8;   // 8 bf16 = 4 VGPRs
typedef __attribute__((ext_vector_type(4))) float f32x4;
typedef __attribute__((ext_vector_type(2))) unsigned int u32x2;

#define NBATCH 4
#define DDIM   128
#define NHEAD  8
#define PTOT   12544
#define CWID   112     // patch grid width
#define NTOK   49      // tokens per 7x7 window
#define PSTR   68      // p_lds row stride (u16 elems)
#define SCALE  0.08838834764831845f

// Round-0 proven LDS layout (u16 units), double-buffered ts/us:
//   buf0: ts 64x128 @0, us 128x64 @8192 ; buf1 @16384 ; pl @32768 (49x68)
//   pcf f32[1352] @36100 ; cs f32[512] @38804 ; total 39828 u16 = 79656 B
// -> 2 blocks/CU, 2 waves/SIMD (structural register floor, calibrated R1-R9).
// R11 reorder: per-head body is  bar -> B(h) -> SM -> P -> A(h+1) -> C(h),
// so the 64 independent A-MFMAs cover C's P-drain + LDS-read latency.
// Barrier audit (1 per head still correct):
//   B(h) reads buf[h&1], written by A(h) in iter h-1 -> iter-h barrier.
//   A(h+1) writes buf[(h+1)&1]; last readers B/C(h-1) are before iter-h barrier.
//   pl/P are wave-private (lgkm drain only).
#define BUFSZ   16384
#define OFF_US  8192
#define OFF_PL  32768
#define OFF_PCF 36100
#define OFF_CS  38804
#define LDS_TOT 39828

__device__ __forceinline__ float bf2f(u16 u) {
    union { u32 i; float f; } x; x.i = ((u32)u) << 16; return x.f;
}
__device__ __forceinline__ u16 f2bf(float f) {
    union { float f; u32 u; } v; v.f = f;
    return (u16)((v.u + 0x7fffu + ((v.u >> 16) & 1u)) >> 16);
}
__device__ __forceinline__ u32 pk2(float a, float b) {
    union { __hip_bfloat162 h; u32 u; } c;
    float2 t; t.x = a; t.y = b;
    c.h = __float22bfloat162_rn(t);
    return c.u;
}
__device__ __forceinline__ int swz128(int row, int col) {
    return row * 128 + ((((col >> 3) ^ (row & 15)) & 15) << 3) + (col & 7);
}

// ws layout: u16 Gt (8 x 128x128, pre-scaled) | u16 Wc (8 x 128x128) | fp32 block
// fp32 block at u16 offset 262144: bcv[1024] | r[1024] | M[1024] | s[8] (r/M/s scaled)
#define WS_WC   131072
#define WS_F32  262144

// ---- prepass (128 blocks = 16 outputs x 8 row-slices) ----
// b<8 -> Wc_h = Wo_h*Wv_h + bcv; b>=8 -> Gt_h = scaled (Wk^T Wq)^T + r/M/s
__global__ void __launch_bounds__(256) prep(
    const float* __restrict__ Wq, const float* __restrict__ Wk,
    const float* __restrict__ Wv, const float* __restrict__ Wo,
    const float* __restrict__ bq, const float* __restrict__ bk,
    const float* __restrict__ bv, u16* __restrict__ ws)
{
    __shared__ u16 lm[18432];           // A-slice 16x128 @0, B 128x128 @2048
    const int tid = threadIdx.x;
    const int bb  = blockIdx.x;
    const int b   = bb >> 3;
    const int sub = bb & 7;
    const bool isG = (b >= 8);
    const int h = b & 7;
    const int r0 = sub * 16;
    float* fb = (float*)(ws + WS_F32);

    if (!isG) {
        for (int idx = tid; idx < 2048; idx += 256) {
            const int lr = idx >> 7, dh = idx & 127;
            lm[swz128(lr, dh)] = f2bf(Wo[(r0 + lr) * 1024 + h * 128 + dh]);
        }
        for (int idx = tid; idx < 16384; idx += 256) {
            const int dh = idx >> 7, d = idx & 127;
            lm[2048 + swz128(d, dh)] = f2bf(Wv[(h * 128 + dh) * 128 + d]);
        }
        if (sub == 0 && tid < 128) {
            float s = 0.f;
            for (int dh = 0; dh < 128; ++dh)
                s += Wo[tid * 1024 + h * 128 + dh] * bv[h * 128 + dh];
            fb[h * 128 + tid] = s;                 // bcv
        }
    } else {
        for (int idx = tid; idx < 2048; idx += 256) {
            const int dh = idx >> 4, lr = idx & 15;
            lm[swz128(lr, dh)] = f2bf(Wk[(h * 128 + dh) * 128 + r0 + lr]);
        }
        for (int idx = tid; idx < 16384; idx += 256) {
            const int dh = idx >> 7, dp = idx & 127;
            lm[2048 + swz128(dp, dh)] = f2bf(Wq[(h * 128 + dh) * 128 + dp]);
        }
        if (sub == 0 && tid < 128) {
            float r = 0.f, m = 0.f;
            for (int dh = 0; dh < 128; ++dh) {
                r += bk[h * 128 + dh] * Wq[(h * 128 + dh) * 128 + tid];
                m += Wk[(h * 128 + dh) * 128 + tid] * bq[h * 128 + dh];
            }
            fb[1024 + h * 128 + tid] = r * SCALE;
            fb[2048 + h * 128 + tid] = m * SCALE;
        }
        if (sub == 0 && tid == 0) {
            float s = 0.f;
            for (int dh = 0; dh < 128; ++dh) s += bk[h * 128 + dh] * bq[h * 128 + dh];
            fb[3072 + h] = s * SCALE;
        }
    }
    __syncthreads();

    const int w = tid >> 6, lane = tid & 63, quad = lane >> 4, lid = lane & 15;
    const f32x4 z4 = {0.f, 0.f, 0.f, 0.f};
    u16* dst = ws + (isG ? 0 : WS_WC) + h * 16384;
    const float gs = isG ? SCALE : 1.0f;
    bf16x8 A[4];
    #pragma unroll
    for (int kt = 0; kt < 4; ++kt)
        A[kt] = *(const bf16x8*)(lm + swz128(lid, kt * 32 + quad * 8));
    #pragma unroll
    for (int ntl = 0; ntl < 2; ++ntl) {
        const int nt = 2 * w + ntl;
        f32x4 acc = z4;
        #pragma unroll
        for (int kt = 0; kt < 4; ++kt) {
            bf16x8 B = *(const bf16x8*)(lm + 2048 + swz128(nt * 16 + lid, kt * 32 + quad * 8));
            acc = __builtin_amdgcn_mfma_f32_16x16x32_bf16(A[kt], B, acc, 0, 0, 0);
        }
        #pragma unroll
        for (int r = 0; r < 4; ++r) {
            const int row = r0 + quad * 4 + r, col = nt * 16 + lid;
            if (isG) dst[col * 128 + row] = f2bf(acc[r] * gs);
            else     dst[row * 128 + col] = f2bf(acc[r]);
        }
    }
}

// stage B body, compile-time wave index WW so xfrag[WW] is a static register use
#define STAGE_B(WW) \
    _Pragma("unroll") \
    for (int mt = 0; mt < 4; ++mt) { \
        _Pragma("unroll") \
        for (int kt = 0; kt < 4; ++kt) { \
            bf16x8 Abf = *(const bf16x8*)(tsb + (mt * 16 + lid) * 128 + ((((kt * 4 + quad) ^ lid) & 15) << 3)); \
            S[mt] = __builtin_amdgcn_mfma_f32_16x16x32_bf16(Abf, xfrag[WW][kt], S[mt], 0, 0, 0); \
        } \
    }

// stage A for head HH into buffers TSB/USB (GA must hold Gt fragments of HH;
// WB loaded in place). Shared by prologue (h=0) and the pipelined loop body.
#define STAGE_A_T(HH, TSB) \
    _Pragma("unroll") \
    for (int mtl = 0; mtl < 2; ++mtl) { \
        const int mt_ = 2 * w + mtl; \
        const f32x4 rb_ = *(const f32x4*)(rP + (HH) * 128 + mt_ * 16 + quad * 4); \
        const int dpb_ = mt_ * 16 + quad * 4; \
        _Pragma("unroll") \
        for (int nt = 0; nt < 4; ++nt) { \
            f32x4 acc_ = z4; \
            _Pragma("unroll") \
            for (int kt = 0; kt < 4; ++kt) \
                acc_ = __builtin_amdgcn_mfma_f32_16x16x32_bf16(GA[mtl][kt], xfrag[nt][kt], acc_, 0, 0, 0); \
            const int i_ = nt * 16 + lid; \
            u32x2 pkv_; \
            pkv_.x = pk2(acc_[0] + rb_[0], acc_[1] + rb_[1]); \
            pkv_.y = pk2(acc_[2] + rb_[2], acc_[3] + rb_[3]); \
            *(u32x2*)((TSB) + i_ * 128 + ((((dpb_ >> 3) ^ (i_ & 15)) & 15) << 3) + (dpb_ & 7)) = pkv_; \
        } \
    }

#define STAGE_A_U(HH, USB) \
    _Pragma("unroll") \
    for (int ntl = 0; ntl < 2; ++ntl) { \
        const int nt_ = 2 * w + ntl; \
        bf16x8 Bw[4]; \
        _Pragma("unroll") \
        for (int kt = 0; kt < 4; ++kt) \
            Bw[kt] = *(const bf16x8*)(Wcw + (HH) * 16384 + (nt_ * 16 + lid) * 128 + kt * 32 + quad * 8); \
        const int dd_ = nt_ * 16 + lid; \
        const float bb_ = bcv[(HH) * 128 + dd_]; \
        _Pragma("unroll") \
        for (int mt = 0; mt < 4; ++mt) { \
            f32x4 acc_ = z4; \
            _Pragma("unroll") \
            for (int kt = 0; kt < 4; ++kt) \
                acc_ = __builtin_amdgcn_mfma_f32_16x16x32_bf16(xfrag[mt][kt], Bw[kt], acc_, 0, 0, 0); \
            const int ib_ = mt * 16 + quad * 4; \
            u32x2 pkv_; \
            pkv_.x = pk2(acc_[0] + bb_, acc_[1] + bb_); \
            pkv_.y = pk2(acc_[2] + bb_, acc_[3] + bb_); \
            *(u32x2*)((USB) + dd_ * 64 + ((((ib_ >> 3) ^ (dd_ & 7)) & 7) << 3) + (ib_ & 7)) = pkv_; \
        } \
    }

// 256 threads = 4 waves; wave w owns query group j in [16w,16w+16).
__global__ void __launch_bounds__(256, 2)
winattn(const float* __restrict__ xg, const u16* __restrict__ ws,
        const float* __restrict__ bo, const float* __restrict__ posf,
        float* __restrict__ out)
{
    __shared__ __align__(16) u16 sm[LDS_TOT];
    u16* xw  = sm;                       // staging overlay on buf0 ts
    u16* pl  = sm + OFF_PL;              // P^T [j][i], wave-private rows
    float* pcf = (float*)(sm + OFF_PCF); // pos bias fp32
    float* cs  = (float*)(sm + OFF_CS);  // c_i per head

    const int tid  = threadIdx.x;
    const int w    = tid >> 6;
    const int lane = tid & 63;
    const int quad = lane >> 4;
    const int lid  = lane & 15;
    // XCD-aware bijective remap (R8-verified: FETCH 72->15 MB)
    const int bx0  = blockIdx.x;
    const int xcd  = bx0 & 7;
    const int idx0 = bx0 >> 3;
    const int n    = idx0 >> 5;
    const int win  = xcd * 32 + (idx0 & 31);
    const int pbase = (win >> 4) * 7 * CWID + (win & 15) * 7;

    const bf16x8 zf = {0,0,0,0,0,0,0,0};
    const f32x4  z4 = {0.f,0.f,0.f,0.f};

    const u16* Gt  = ws;
    const u16* Wcw = ws + WS_WC;
    const float* fb  = (const float*)(ws + WS_F32);
    const float* bcv = fb;
    const float* rP  = fb + 1024;
    const float* MP  = fb + 2048;
    const float* sP  = fb + 3072;

    // ---- stage pos table + x window ----
    for (int i = tid; i < 169 * NHEAD; i += 256) pcf[i] = posf[i];
    const float* xn = xg + n * DDIM * PTOT;
    for (int idx = tid; idx < DDIM * NTOK; idx += 256) {
        int d = idx / NTOK;
        int t = idx - d * NTOK;
        int a = t / 7, b = t - a * 7;
        xw[swz128(t, d)] = f2bf(xn[d * PTOT + pbase + a * CWID + b]);
    }
    __syncthreads();

    // ---- hoist x fragments (A-layout == B-layout: lane lid = token, quad*8 = d) ----
    bf16x8 xfrag[4][4];
    #pragma unroll
    for (int mt = 0; mt < 4; ++mt)
        #pragma unroll
        for (int kt = 0; kt < 4; ++kt)
            xfrag[mt][kt] = (mt * 16 + lid < NTOK)
                ? *(const bf16x8*)(xw + swz128(mt * 16 + lid, kt * 32 + quad * 8)) : zf;
    const int j = 16 * w + lid;

    // ---- head-0 GA prefetched; c_i compute hides the latency ----
    bf16x8 GA[2][4];
    #pragma unroll
    for (int mtl = 0; mtl < 2; ++mtl)
        #pragma unroll
        for (int kt = 0; kt < 4; ++kt)
            GA[mtl][kt] = *(const bf16x8*)(Gt + ((2 * w + mtl) * 16 + lid) * 128 + kt * 32 + quad * 8);

    // ---- c_i tables (scaled): cs[h][i] = x_i . M_h + s_h ----
    for (int hh = w; hh < NHEAD; hh += 4) {
        const float sh = sP[hh];
        #pragma unroll
        for (int mt = 0; mt < 4; ++mt) {
            float c = 0.f;
            #pragma unroll
            for (int kt = 0; kt < 4; ++kt)
                #pragma unroll
                for (int jj = 0; jj < 8; ++jj)
                    c += bf2f((u16)xfrag[mt][kt][jj]) * MP[hh * 128 + kt * 32 + quad * 8 + jj];
            c += __shfl_xor(c, 16);
            c += __shfl_xor(c, 32);
            if (quad == 0) cs[hh * 64 + mt * 16 + lid] = c + sh;
        }
    }
    __syncthreads();   // all waves done reading xw (buf0 ts overlays it); cs stores issued

    f32x4 outacc[8];
    #pragma unroll
    for (int nt = 0; nt < 8; ++nt) outacc[nt] = z4;

    const int jc = j < NTOK ? j : NTOK - 1;
    const int aj = jc / 7, bj = jc - aj * 7;   // head-invariant

    // ---- prologue: A(0) into buf0 (GA holds head 0; WB in place) ----
    __builtin_amdgcn_s_setprio(1);
    STAGE_A_T(0, sm)
    STAGE_A_U(0, sm + OFF_US)
    __builtin_amdgcn_s_setprio(0);

    #pragma unroll 2
    for (int h = 0; h < NHEAD; ++h) {
        u16* tsb = sm + (h & 1) * BUFSZ;            // T^T as ts[i][d'] swizzled
        u16* usb = tsb + OFF_US;                    // U as us[dd][i] swizzled
        u16* tsb2 = sm + ((h + 1) & 1) * BUFSZ;     // next head's buffers
        u16* usb2 = tsb2 + OFF_US;

        // ---- prefetch next head's GA: consumed later THIS iteration at A(h+1);
        //      in flight across the counted barrier + stage B ----
        if (h < NHEAD - 1) {
            const int hn = h + 1;
            #pragma unroll
            for (int mtl = 0; mtl < 2; ++mtl)
                #pragma unroll
                for (int kt = 0; kt < 4; ++kt)
                    GA[mtl][kt] = *(const bf16x8*)(Gt + hn * 16384 + ((2 * w + mtl) * 16 + lid) * 128 + kt * 32 + quad * 8);
        }

        // counted barrier: prior A's ds_writes must be visible (lgkmcnt 0) but
        // global prefetches may stay in flight (no vmcnt drain)
        asm volatile("s_waitcnt lgkmcnt(0)" ::: "memory");
        __builtin_amdgcn_s_barrier();
        asm volatile("" ::: "memory");

        // ======== stage B: S = T x X_j^T (+cs+pos), softmax (no max-shift) ========
        f32x4 S[4];
        #pragma unroll
        for (int mt = 0; mt < 4; ++mt) S[mt] = z4;
        __builtin_amdgcn_s_setprio(1);
        if      (w == 0) { STAGE_B(0) }
        else if (w == 1) { STAGE_B(1) }
        else if (w == 2) { STAGE_B(2) }
        else             { STAGE_B(3) }
        __builtin_amdgcn_s_setprio(0);

        float sv[4][4];
        float ssum = 0.f;
        #pragma unroll
        for (int mt = 0; mt < 4; ++mt) {
            const f32x4 csv = *(const f32x4*)(cs + h * 64 + mt * 16 + quad * 4);
            #pragma unroll
            for (int r = 0; r < 4; ++r) {
                const int ii = mt * 16 + quad * 4 + r;
                float e;
                if (ii < NTOK) {
                    const int ai = ii / 7, bi = ii - ai * 7;
                    const int rel = (ai - aj + 6) + 13 * (bi - bj + 6);
                    e = __expf(S[mt][r] + csv[r] + pcf[rel * NHEAD + h]);
                } else {
                    e = 0.0f;
                }
                sv[mt][r] = e;
                ssum += e;
            }
        }
        ssum += __shfl_xor(ssum, 16);
        ssum += __shfl_xor(ssum, 32);
        const float inv = __builtin_amdgcn_rcpf(ssum);   // ~1e-5 rel err << bf16 P
        if (j < NTOK) {
            #pragma unroll
            for (int mt = 0; mt < 4; ++mt) {
                u32x2 pkv;
                pkv.x = pk2(sv[mt][0] * inv, sv[mt][1] * inv);
                pkv.y = pk2(sv[mt][2] * inv, sv[mt][3] * inv);
                *(u32x2*)(pl + j * PSTR + mt * 16 + quad * 4) = pkv;
            }
        }
        // P rows are wave-private: same-wave LDS RAW needs only an lgkmcnt drain.
        asm volatile("s_waitcnt lgkmcnt(0)" ::: "memory");

        // ======== pipelined stage A(h+1) into the other buffer:
        //          64 independent MFMAs cover C's LDS-read latency ========
        if (h < NHEAD - 1) {
            __builtin_amdgcn_s_setprio(1);
            STAGE_A_T(h + 1, tsb2)
            STAGE_A_U(h + 1, usb2)
            __builtin_amdgcn_s_setprio(0);
        }

        // ======== stage C: outacc += P^T x U ========
        __builtin_amdgcn_s_setprio(1);
        #pragma unroll
        for (int kt = 0; kt < 2; ++kt) {
            union { bf16x8 v; u32 u[4]; } Af;
            #pragma unroll
            for (int q2 = 0; q2 < 4; ++q2)
                Af.u[q2] = *(const u32*)(pl + jc * PSTR + kt * 32 + quad * 8 + 2 * q2);
            #pragma unroll
            for (int nt = 0; nt < 8; ++nt) {
                const int dd = nt * 16 + lid;
                bf16x8 Bu = *(const bf16x8*)(usb + dd * 64 + ((((kt * 4 + quad) ^ (dd & 7)) & 7) << 3));
                outacc[nt] = __builtin_amdgcn_mfma_f32_16x16x32_bf16(Af.v, Bu, outacc[nt], 0, 0, 0);
            }
        }
        __builtin_amdgcn_s_setprio(0);
        // no end-of-head barrier: A(h+1) wrote the OTHER ts/us buffer; the
        // iteration-(h+1) barrier hands it to B(h+1).
    }

    // ======== epilogue: out[n][dd][p(j)] = acc + bo[dd]  (fp32 output) ========
    float* outp = out + n * DDIM * PTOT;
    #pragma unroll
    for (int nt = 0; nt < 8; ++nt) {
        const int dd = nt * 16 + lid;
        const float bov = bo[dd];
        #pragma unroll
        for (int r = 0; r < 4; ++r) {
            const int jj = 16 * w + quad * 4 + r;
            if (jj < NTOK) {
                const int a = jj / 7, b = jj - a * 7;
                outp[dd * PTOT + pbase + a * CWID + b] = outacc[nt][r] + bov;
            }
        }
    }
}

extern "C" void kernel_launch(void* const* d_in, const int* in_sizes, int n_in,
                              void* d_out, int out_size, void* d_ws, size_t ws_size,
                              hipStream_t stream) {
    (void)in_sizes; (void)n_in; (void)ws_size; (void)out_size;
    prep<<<128, 256, 0, stream>>>((const float*)d_in[1], (const float*)d_in[3],
                                  (const float*)d_in[5], (const float*)d_in[7],
                                  (const float*)d_in[2], (const float*)d_in[4],
                                  (const float*)d_in[6], (u16*)d_ws);
    winattn<<<NBATCH * 256, 256, 0, stream>>>(
        (const float*)d_in[0], (const u16*)d_ws,
        (const float*)d_in[8], (const float*)d_in[9], (float*)d_out);
}